// Round 1
// baseline (1255.492 us; speedup 1.0000x reference)
//
#include <hip/hip_runtime.h>
#include <math.h>

// Blended-expert MLP: per layer, C[b,o] = sum_{e,i} wb[b,e]*x[b,i]*W[e,o,i] + sum_e wb[b,e]*Bias[e,o]
// Treated as GEMM M=2048, N=Dout, K=8*Din with A synthesized (wb-scaled x) per expert block.
// fp32 baseline: 64x64 block tile, 4x4 micro-tile, BK=16 LDS staging.

#define NEXP 8
#define BM 64
#define BN 64
#define BK 16
#define PAD 4   // LDS row pad: keeps float4 alignment (stride 68 floats = 17*16B)

__global__ __launch_bounds__(256) void moe_layer_f32(
    const float* __restrict__ X,     // [2048, Din]
    const float* __restrict__ W,     // [NEXP, Dout, Din]
    const float* __restrict__ Bias,  // [NEXP, Dout]
    const float* __restrict__ WB,    // [2048, NEXP]
    float* __restrict__ Y,           // [2048, Dout]
    int Din, int Dout, int act)
{
    __shared__ float As[BK][BM + PAD];  // As[k][m], k-major for vector compute reads
    __shared__ float Bs[BK][BN + PAD];  // Bs[k][n]

    const int tid = threadIdx.x;
    const int tm  = tid >> 4;        // 0..15
    const int tn  = tid & 15;        // 0..15
    const int m0  = blockIdx.y * BM;
    const int n0  = blockIdx.x * BN;

    // staging: 256 threads cover 64 rows x 16 cols, one float4 each
    const int lr = tid >> 2;         // 0..63
    const int lc = (tid & 3) << 2;   // 0,4,8,12

    float acc[4][4] = {};

    const float* xrow  = X  + (size_t)(m0 + lr) * Din;
    const float* wbrow = WB + (size_t)(m0 + lr) * NEXP;
    const float* wrow0 = W  + (size_t)(n0 + lr) * Din;

    for (int e = 0; e < NEXP; ++e) {
        const float wbe = wbrow[e];
        const float* wrow = wrow0 + (size_t)e * Dout * Din;
        for (int k0 = 0; k0 < Din; k0 += BK) {
            // global loads issued before barrier for latency overlap
            float4 av = *(const float4*)(xrow + k0 + lc);
            float4 bv = *(const float4*)(wrow + k0 + lc);
            __syncthreads();   // previous stage's LDS reads complete
            As[lc + 0][lr] = av.x * wbe;   // fold blend weight into A
            As[lc + 1][lr] = av.y * wbe;
            As[lc + 2][lr] = av.z * wbe;
            As[lc + 3][lr] = av.w * wbe;
            Bs[lc + 0][lr] = bv.x;
            Bs[lc + 1][lr] = bv.y;
            Bs[lc + 2][lr] = bv.z;
            Bs[lc + 3][lr] = bv.w;
            __syncthreads();
            #pragma unroll
            for (int k = 0; k < BK; ++k) {
                float4 a = *(const float4*)&As[k][tm << 2];
                float4 b = *(const float4*)&Bs[k][tn << 2];
                acc[0][0] += a.x * b.x; acc[0][1] += a.x * b.y;
                acc[0][2] += a.x * b.z; acc[0][3] += a.x * b.w;
                acc[1][0] += a.y * b.x; acc[1][1] += a.y * b.y;
                acc[1][2] += a.y * b.z; acc[1][3] += a.y * b.w;
                acc[2][0] += a.z * b.x; acc[2][1] += a.z * b.y;
                acc[2][2] += a.z * b.z; acc[2][3] += a.z * b.w;
                acc[3][0] += a.w * b.x; acc[3][1] += a.w * b.y;
                acc[3][2] += a.w * b.z; acc[3][3] += a.w * b.w;
            }
        }
    }

    // epilogue: blended bias + optional ELU, vectorized store
    #pragma unroll
    for (int im = 0; im < 4; ++im) {
        const int m = m0 + (tm << 2) + im;
        const float* wbm = WB + (size_t)m * NEXP;
        float wv[NEXP];
        #pragma unroll
        for (int e = 0; e < NEXP; ++e) wv[e] = wbm[e];
        #pragma unroll
        for (int in = 0; in < 4; ++in) {
            const int n = n0 + (tn << 2) + in;
            float bsum = 0.f;
            #pragma unroll
            for (int e = 0; e < NEXP; ++e) bsum += wv[e] * Bias[(size_t)e * Dout + n];
            float v = acc[im][in] + bsum;
            if (act) v = v > 0.f ? v : expm1f(v);   // jax.nn.elu
            acc[im][in] = v;
        }
        float4 o = make_float4(acc[im][0], acc[im][1], acc[im][2], acc[im][3]);
        *(float4*)(Y + (size_t)m * Dout + n0 + (tn << 2)) = o;
    }
}

extern "C" void kernel_launch(void* const* d_in, const int* in_sizes, int n_in,
                              void* d_out, int out_size, void* d_ws, size_t ws_size,
                              hipStream_t stream)
{
    (void)in_sizes; (void)n_in; (void)out_size; (void)ws_size;
    const float* wb = (const float*)d_in[0];  // [2048, 8]
    const float* x  = (const float*)d_in[1];  // [2048, 512]
    const float* W0 = (const float*)d_in[2];  // [8, 1024, 512]
    const float* B0 = (const float*)d_in[3];  // [8, 1024]
    const float* W1 = (const float*)d_in[4];  // [8, 1024, 1024]
    const float* B1 = (const float*)d_in[5];  // [8, 1024]
    const float* W2 = (const float*)d_in[6];  // [8, 512, 1024]
    const float* B2 = (const float*)d_in[7];  // [8, 512]
    float* out = (float*)d_out;

    const int BATCH = 2048;
    float* x1 = (float*)d_ws;                   // [2048, 1024]
    float* x2 = x1 + (size_t)BATCH * 1024;      // [2048, 1024]  (ws: 16 MB used)

    dim3 blk(256);
    moe_layer_f32<<<dim3(1024 / BN, BATCH / BM), blk, 0, stream>>>(x,  W0, B0, wb, x1, 512,  1024, 1);
    moe_layer_f32<<<dim3(1024 / BN, BATCH / BM), blk, 0, stream>>>(x1, W1, B1, wb, x2, 1024, 1024, 1);
    moe_layer_f32<<<dim3(512  / BN, BATCH / BM), blk, 0, stream>>>(x2, W2, B2, wb, out, 1024, 512, 0);
}

// Round 2
// 231.624 us; speedup vs baseline: 5.4204x; 5.4204x over previous
//
#include <hip/hip_runtime.h>
#include <math.h>

typedef __attribute__((ext_vector_type(8))) short bf16x8;   // 8 bf16 = 4 VGPRs
typedef __attribute__((ext_vector_type(4))) float f32x4;    // MFMA acc

#define NEXP 8
#define BATCH 2048

__device__ __forceinline__ unsigned short f2bf(float f) {
    union { float f; unsigned u; } v; v.f = f;
    unsigned r = v.u + 0x7FFFu + ((v.u >> 16) & 1u);   // RTNE
    return (unsigned short)(r >> 16);
}

__global__ void cvt_f32_bf16(const float* __restrict__ src,
                             unsigned short* __restrict__ dst, int n4) {
    int i = blockIdx.x * blockDim.x + threadIdx.x;
    if (i >= n4) return;
    float4 v = ((const float4*)src)[i];
    ushort4 o;
    o.x = f2bf(v.x); o.y = f2bf(v.y); o.z = f2bf(v.z); o.w = f2bf(v.w);
    ((ushort4*)dst)[i] = o;
}

// async global->LDS, 16B per lane; LDS dst is wave-uniform base + lane*16
__device__ __forceinline__ void gload_lds16(const unsigned short* g, void* lds_dst) {
    __builtin_amdgcn_global_load_lds(
        (const __attribute__((address_space(1))) unsigned int*)g,
        (__attribute__((address_space(3))) unsigned int*)lds_dst,
        16, 0, 0);
}

// Blended-expert layer, bf16 MFMA.
// Block: 64x64 output tile, 4 waves; wave w owns experts {2w, 2w+1} with
// separate accumulators, scaled by wb at the end (exact fp32 blend).
// LDS staging: xs[64][32] bf16 (shared) + 8 x Wtile[64][32] bf16, all via
// global_load_lds dwordx4. Epilogue: cross-wave reduce via 64KB LDS partials.
__global__ __launch_bounds__(256, 2) void moe_mfma(
    const unsigned short* __restrict__ Xb,   // [BATCH, Din] bf16
    const unsigned short* __restrict__ Wb,   // [NEXP, Dout, Din] bf16
    const float* __restrict__ Bias,          // [NEXP, Dout]
    const float* __restrict__ WBl,           // [BATCH, NEXP]
    void* __restrict__ Yout,                 // bf16 or f32 [BATCH, Dout]
    int Din, int Dout, int act, int out_bf16)
{
    __shared__ __align__(16) float lds_f[16384];       // 64 KB (staging 36KB / partials 64KB union)
    unsigned short* lds_h = (unsigned short*)lds_f;

    const int tid = threadIdx.x;
    const int w   = tid >> 6;        // wave 0..3
    const int l   = tid & 63;
    const int lh  = l >> 4;          // 0..3
    const int ll  = l & 15;          // 0..15
    const int m0  = blockIdx.y * 64;
    const int n0  = blockIdx.x * 64;
    const int e0  = 2 * w, e1 = 2 * w + 1;

    f32x4 acc0[4][4], acc1[4][4];
    #pragma unroll
    for (int t = 0; t < 4; ++t)
        #pragma unroll
        for (int u = 0; u < 4; ++u)
            #pragma unroll
            for (int i = 0; i < 4; ++i) { acc0[t][u][i] = 0.f; acc1[t][u][i] = 0.f; }

    // staging lane mapping: 64 lanes = 16 rows x 4 chunks of 16B (8 bf16)
    const int srow = l >> 2;          // 0..15
    const int scol = (l & 3) * 8;     // bf16 col offset

    const unsigned short* xg  = Xb + (size_t)(m0 + w * 16 + srow) * Din + scol;
    const unsigned short* wg0 = Wb + ((size_t)e0 * Dout + n0 + srow) * Din + scol;
    const unsigned short* wg1 = Wb + ((size_t)e1 * Dout + n0 + srow) * Din + scol;
    char* xdst  = (char*)lds_f + w * 1024;            // xs rows 16w..16w+15
    char* wdst0 = (char*)lds_f + 4096 + e0 * 4096;
    char* wdst1 = (char*)lds_f + 4096 + e1 * 4096;
    const size_t wrowstride = (size_t)16 * Din;       // 16 rows per 1KB chunk

    const int nk = Din >> 5;          // BK = 32
    for (int kk = 0; kk < nk; ++kk) {
        const int k0 = kk << 5;
        __syncthreads();                               // prev iteration's readers done
        gload_lds16(xg + k0, xdst);
        #pragma unroll
        for (int j = 0; j < 4; ++j) {
            gload_lds16(wg0 + k0 + (size_t)j * wrowstride, wdst0 + j * 1024);
            gload_lds16(wg1 + k0 + (size_t)j * wrowstride, wdst1 + j * 1024);
        }
        __syncthreads();                               // vmcnt(0) drain -> tiles visible

        bf16x8 a[4];
        #pragma unroll
        for (int t = 0; t < 4; ++t)
            a[t] = *(const bf16x8*)(lds_h + t * 512 + ll * 32 + lh * 8);
        const unsigned short* wp0 = lds_h + 2048 + e0 * 2048;
        const unsigned short* wp1 = lds_h + 2048 + e1 * 2048;
        #pragma unroll
        for (int u = 0; u < 4; ++u) {
            bf16x8 b0 = *(const bf16x8*)(wp0 + u * 512 + ll * 32 + lh * 8);
            bf16x8 b1 = *(const bf16x8*)(wp1 + u * 512 + ll * 32 + lh * 8);
            #pragma unroll
            for (int t = 0; t < 4; ++t) {
                acc0[t][u] = __builtin_amdgcn_mfma_f32_16x16x32_bf16(a[t], b0, acc0[t][u], 0, 0, 0);
                acc1[t][u] = __builtin_amdgcn_mfma_f32_16x16x32_bf16(a[t], b1, acc1[t][u], 0, 0, 0);
            }
        }
    }
    __syncthreads();   // all frag reads done before partials overwrite staging LDS

    // blended bias values for this wave's two experts
    float b0v[4], b1v[4];
    #pragma unroll
    for (int u = 0; u < 4; ++u) {
        int n = n0 + u * 16 + ll;
        b0v[u] = Bias[(size_t)e0 * Dout + n];
        b1v[u] = Bias[(size_t)e1 * Dout + n];
    }
    // C/D layout: reg r of lane l -> C[m0+16t+4*lh+r][n0+16u+ll]  (m89-verified)
    float* part = lds_f + w * 4096;    // [64][64] f32 per wave
    #pragma unroll
    for (int t = 0; t < 4; ++t) {
        #pragma unroll
        for (int r = 0; r < 4; ++r) {
            const int mloc = t * 16 + lh * 4 + r;
            float2 wbp = ((const float2*)(WBl + (size_t)(m0 + mloc) * NEXP))[w];
            #pragma unroll
            for (int u = 0; u < 4; ++u) {
                float v = wbp.x * (acc0[t][u][r] + b0v[u]) + wbp.y * (acc1[t][u][r] + b1v[u]);
                part[mloc * 64 + u * 16 + ll] = v;
            }
        }
    }
    __syncthreads();

    // reduce 4 wave-partials + activation + store; thread -> 4x4 sub-block
    const int tn    = tid & 15;
    const int nloc  = tn * 4;
    const int mloc0 = (tid >> 4) * 4;
    #pragma unroll
    for (int i = 0; i < 4; ++i) {
        const int mloc = mloc0 + i;
        float4 s = *(const float4*)(lds_f + mloc * 64 + nloc);
        #pragma unroll
        for (int p = 1; p < 4; ++p) {
            float4 q = *(const float4*)(lds_f + p * 4096 + mloc * 64 + nloc);
            s.x += q.x; s.y += q.y; s.z += q.z; s.w += q.w;
        }
        if (act) {
            s.x = s.x > 0.f ? s.x : expm1f(s.x);
            s.y = s.y > 0.f ? s.y : expm1f(s.y);
            s.z = s.z > 0.f ? s.z : expm1f(s.z);
            s.w = s.w > 0.f ? s.w : expm1f(s.w);
        }
        const size_t off = (size_t)(m0 + mloc) * Dout + n0 + nloc;
        if (out_bf16) {
            ushort4 o;
            o.x = f2bf(s.x); o.y = f2bf(s.y); o.z = f2bf(s.z); o.w = f2bf(s.w);
            *(ushort4*)((unsigned short*)Yout + off) = o;
        } else {
            *(float4*)((float*)Yout + off) = s;
        }
    }
}

// ---------------- fp32 fallback (round-1 kernel) for small ws_size ----------------
#define BM 64
#define BN 64
#define BK 16
#define PAD 4

__global__ __launch_bounds__(256) void moe_layer_f32(
    const float* __restrict__ X, const float* __restrict__ W,
    const float* __restrict__ Bias, const float* __restrict__ WB,
    float* __restrict__ Y, int Din, int Dout, int act)
{
    __shared__ float As[BK][BM + PAD];
    __shared__ float Bs[BK][BN + PAD];
    const int tid = threadIdx.x;
    const int tm = tid >> 4, tn = tid & 15;
    const int m0 = blockIdx.y * BM, n0 = blockIdx.x * BN;
    const int lr = tid >> 2, lc = (tid & 3) << 2;
    float acc[4][4] = {};
    const float* xrow  = X  + (size_t)(m0 + lr) * Din;
    const float* wbrow = WB + (size_t)(m0 + lr) * NEXP;
    const float* wrow0 = W  + (size_t)(n0 + lr) * Din;
    for (int e = 0; e < NEXP; ++e) {
        const float wbe = wbrow[e];
        const float* wrow = wrow0 + (size_t)e * Dout * Din;
        for (int k0 = 0; k0 < Din; k0 += BK) {
            float4 av = *(const float4*)(xrow + k0 + lc);
            float4 bv = *(const float4*)(wrow + k0 + lc);
            __syncthreads();
            As[lc+0][lr] = av.x*wbe; As[lc+1][lr] = av.y*wbe;
            As[lc+2][lr] = av.z*wbe; As[lc+3][lr] = av.w*wbe;
            Bs[lc+0][lr] = bv.x; Bs[lc+1][lr] = bv.y;
            Bs[lc+2][lr] = bv.z; Bs[lc+3][lr] = bv.w;
            __syncthreads();
            #pragma unroll
            for (int k = 0; k < BK; ++k) {
                float4 a = *(const float4*)&As[k][tm << 2];
                float4 b = *(const float4*)&Bs[k][tn << 2];
                acc[0][0]+=a.x*b.x; acc[0][1]+=a.x*b.y; acc[0][2]+=a.x*b.z; acc[0][3]+=a.x*b.w;
                acc[1][0]+=a.y*b.x; acc[1][1]+=a.y*b.y; acc[1][2]+=a.y*b.z; acc[1][3]+=a.y*b.w;
                acc[2][0]+=a.z*b.x; acc[2][1]+=a.z*b.y; acc[2][2]+=a.z*b.z; acc[2][3]+=a.z*b.w;
                acc[3][0]+=a.w*b.x; acc[3][1]+=a.w*b.y; acc[3][2]+=a.w*b.z; acc[3][3]+=a.w*b.w;
            }
        }
    }
    #pragma unroll
    for (int im = 0; im < 4; ++im) {
        const int m = m0 + (tm << 2) + im;
        const float* wbm = WB + (size_t)m * NEXP;
        float wv[NEXP];
        #pragma unroll
        for (int e = 0; e < NEXP; ++e) wv[e] = wbm[e];
        #pragma unroll
        for (int in = 0; in < 4; ++in) {
            const int n = n0 + (tn << 2) + in;
            float bsum = 0.f;
            #pragma unroll
            for (int e = 0; e < NEXP; ++e) bsum += wv[e] * Bias[(size_t)e * Dout + n];
            float v = acc[im][in] + bsum;
            if (act) v = v > 0.f ? v : expm1f(v);
            acc[im][in] = v;
        }
        float4 o = make_float4(acc[im][0], acc[im][1], acc[im][2], acc[im][3]);
        *(float4*)(Y + (size_t)m * Dout + n0 + (tn << 2)) = o;
    }
}

extern "C" void kernel_launch(void* const* d_in, const int* in_sizes, int n_in,
                              void* d_out, int out_size, void* d_ws, size_t ws_size,
                              hipStream_t stream)
{
    (void)in_sizes; (void)n_in; (void)out_size;
    const float* wb = (const float*)d_in[0];
    const float* x  = (const float*)d_in[1];
    const float* W0 = (const float*)d_in[2];
    const float* B0 = (const float*)d_in[3];
    const float* W1 = (const float*)d_in[4];
    const float* B1 = (const float*)d_in[5];
    const float* W2 = (const float*)d_in[6];
    const float* B2 = (const float*)d_in[7];
    float* out = (float*)d_out;

    const size_t NW0 = (size_t)8*1024*512, NW1 = (size_t)8*1024*1024, NW2 = (size_t)8*512*1024;
    const size_t NX0 = (size_t)BATCH*512, NX1 = (size_t)BATCH*1024;
    const size_t need = (NW0 + NW1 + NW2 + NX0 + 2 * NX1) * 2;   // ~44 MB bf16

    if (ws_size >= need) {
        unsigned short* Wb0 = (unsigned short*)d_ws;
        unsigned short* Wb1 = Wb0 + NW0;
        unsigned short* Wb2 = Wb1 + NW1;
        unsigned short* xb0 = Wb2 + NW2;
        unsigned short* xb1 = xb0 + NX0;
        unsigned short* xb2 = xb1 + NX1;
        cvt_f32_bf16<<<NW0/4/256, 256, 0, stream>>>(W0, Wb0, NW0/4);
        cvt_f32_bf16<<<NW1/4/256, 256, 0, stream>>>(W1, Wb1, NW1/4);
        cvt_f32_bf16<<<NW2/4/256, 256, 0, stream>>>(W2, Wb2, NW2/4);
        cvt_f32_bf16<<<NX0/4/256, 256, 0, stream>>>(x,  xb0, NX0/4);
        moe_mfma<<<dim3(1024/64, BATCH/64), 256, 0, stream>>>(xb0, Wb0, B0, wb, xb1, 512,  1024, 1, 1);
        moe_mfma<<<dim3(1024/64, BATCH/64), 256, 0, stream>>>(xb1, Wb1, B1, wb, xb2, 1024, 1024, 1, 1);
        moe_mfma<<<dim3(512/64,  BATCH/64), 256, 0, stream>>>(xb2, Wb2, B2, wb, out, 1024, 512,  0, 0);
    } else {
        float* x1 = (float*)d_ws;
        float* x2 = x1 + (size_t)BATCH * 1024;
        moe_layer_f32<<<dim3(1024/BN, BATCH/BM), 256, 0, stream>>>(x,  W0, B0, wb, x1, 512,  1024, 1);
        moe_layer_f32<<<dim3(1024/BN, BATCH/BM), 256, 0, stream>>>(x1, W1, B1, wb, x2, 1024, 1024, 1);
        moe_layer_f32<<<dim3(512/BN,  BATCH/BM), 256, 0, stream>>>(x2, W2, B2, wb, out, 1024, 512,  0);
    }
}